// Round 1
// baseline (51.611 us; speedup 1.0000x reference)
//
#include <hip/hip_runtime.h>

// Deimv2LQE: out = scores + MLP(top4-softmax-stats(pred_corners))
// B=64, L=4096 -> 262144 rows; per row 132 f32 (4 corners x 33 bins).
// stats: per corner softmax over 33 bins, top-4 probs + their mean -> 20 dims
// MLP: 20 -> 64 (relu) -> 1.

#define ROWS_PER_BLOCK 256
#define CHUNK_ROWS 64
#define THREADS 256

__global__ __launch_bounds__(THREADS)
void lqe_kernel(const float* __restrict__ scores,
                const float* __restrict__ pc,
                const float* __restrict__ w1,
                const float* __restrict__ b1,
                const float* __restrict__ w2,
                const float* __restrict__ b2,
                float* __restrict__ out)
{
    // 64 rows * 132 floats staged per chunk (33792 B), stats for 256 rows
    // stored with stride 21 (odd -> conflict-free lane access) (21504 B).
    __shared__ float sm_stage[CHUNK_ROWS * 132];
    __shared__ float sm_stat[ROWS_PER_BLOCK * 21];

    const int tid = threadIdx.x;
    const long long blockRowBase = (long long)blockIdx.x * ROWS_PER_BLOCK;

    #pragma unroll
    for (int it = 0; it < 4; ++it) {
        // ---- stage 64 rows = 8448 floats = 2112 float4, coalesced ----
        const float4* src =
            (const float4*)(pc + (blockRowBase + (long long)it * CHUNK_ROWS) * 132);
        float4* dst4 = (float4*)sm_stage;
        #pragma unroll
        for (int i = 0; i < 8; ++i)
            dst4[tid + i * THREADS] = src[tid + i * THREADS];
        if (tid < 64) dst4[tid + 2048] = src[tid + 2048];
        __syncthreads();

        // ---- 256 corner tasks: row r = tid>>2 (in chunk), corner c = tid&3 ----
        // LDS addr = tid*33 (odd stride -> conflict-free)
        const float* v = sm_stage + tid * 33;
        float x[33];
        #pragma unroll
        for (int k = 0; k < 33; ++k) x[k] = v[k];

        // top-4 (descending t0..t3), branchless insertion network
        float t0 = x[0], t1 = x[1], t2 = x[2], t3 = x[3];
        float a;
        a = fmaxf(t0, t1); t1 = fminf(t0, t1); t0 = a;
        a = fmaxf(t2, t3); t3 = fminf(t2, t3); t2 = a;
        a = fmaxf(t0, t2); t2 = fminf(t0, t2); t0 = a;
        a = fmaxf(t1, t3); t3 = fminf(t1, t3); t1 = a;
        a = fmaxf(t1, t2); t2 = fminf(t1, t2); t1 = a;
        #pragma unroll
        for (int k = 4; k < 33; ++k) {
            float xx = x[k];
            a = fmaxf(t0, xx); xx = fminf(t0, xx); t0 = a;
            a = fmaxf(t1, xx); xx = fminf(t1, xx); t1 = a;
            a = fmaxf(t2, xx); xx = fminf(t2, xx); t2 = a;
            t3 = fmaxf(t3, xx);
        }

        // softmax denominator (t0 is the max)
        float s = 0.f;
        #pragma unroll
        for (int k = 0; k < 33; ++k) s += __expf(x[k] - t0);
        const float inv = 1.0f / s;
        const float p0 = inv;                      // exp(0)/s
        const float p1 = __expf(t1 - t0) * inv;
        const float p2 = __expf(t2 - t0) * inv;
        const float p3 = __expf(t3 - t0) * inv;
        const float pm = 0.25f * (p0 + p1 + p2 + p3);

        const int r = tid >> 2, c = tid & 3;
        float* sd = sm_stat + (it * CHUNK_ROWS + r) * 21 + c * 5;
        sd[0] = p0; sd[1] = p1; sd[2] = p2; sd[3] = p3; sd[4] = pm;
        __syncthreads();   // protects sm_stage reuse + sm_stat visibility
    }

    // ---- MLP: one thread per row; weight indices are wave-uniform -> s_load ----
    float st[20];
    #pragma unroll
    for (int k = 0; k < 20; ++k) st[k] = sm_stat[tid * 21 + k];

    float acc = 0.f;
    #pragma unroll
    for (int jc = 0; jc < 4; ++jc) {
        float h[16];
        #pragma unroll
        for (int j = 0; j < 16; ++j) h[j] = b1[jc * 16 + j];
        #pragma unroll
        for (int k = 0; k < 20; ++k) {
            #pragma unroll
            for (int j = 0; j < 16; ++j)
                h[j] = fmaf(st[k], w1[k * 64 + jc * 16 + j], h[j]);
        }
        #pragma unroll
        for (int j = 0; j < 16; ++j)
            acc = fmaf(fmaxf(h[j], 0.f), w2[jc * 16 + j], acc);
    }

    const long long grow = blockRowBase + tid;
    out[grow] = scores[grow] + acc + b2[0];
}

extern "C" void kernel_launch(void* const* d_in, const int* in_sizes, int n_in,
                              void* d_out, int out_size, void* d_ws, size_t ws_size,
                              hipStream_t stream) {
    const float* scores = (const float*)d_in[0];
    const float* pc     = (const float*)d_in[1];
    const float* w1     = (const float*)d_in[2];
    const float* b1     = (const float*)d_in[3];
    const float* w2     = (const float*)d_in[4];
    const float* b2     = (const float*)d_in[5];
    float* out = (float*)d_out;

    const int rows = out_size;                 // B*L = 262144
    const int blocks = rows / ROWS_PER_BLOCK;  // 1024
    lqe_kernel<<<blocks, THREADS, 0, stream>>>(scores, pc, w1, b1, w2, b2, out);
}

// Round 2
// 50.605 us; speedup vs baseline: 1.0199x; 1.0199x over previous
//
#include <hip/hip_runtime.h>

// Deimv2LQE: out = scores + MLP(top4-softmax-stats(pred_corners))
// 262144 rows; per row 132 f32 (4 corners x 33 bins).
// R2: 64 rows/block (4096 blocks), single stage chunk, 2 barriers,
//     LDS = 39168 B -> 4 blocks/CU; MLP on wave 0 (one thread per row,
//     wave-uniform weight indices -> s_load through constant cache).

#define THREADS 256
#define ROWS 64

__global__ __launch_bounds__(THREADS)
void lqe_kernel(const float* __restrict__ scores,
                const float* __restrict__ pc,
                const float* __restrict__ w1,
                const float* __restrict__ b1,
                const float* __restrict__ w2,
                const float* __restrict__ b2,
                float* __restrict__ out)
{
    __shared__ float sm_stage[ROWS * 132];   // 33792 B
    __shared__ float sm_stat[ROWS * 21];     // 5376 B (stride 21: odd -> <=2-way)

    const int tid = threadIdx.x;
    const long long rowBase = (long long)blockIdx.x * ROWS;

    // ---- stage 64 rows = 8448 floats = 2112 float4, fully coalesced ----
    const float4* src = (const float4*)(pc + rowBase * 132);
    float4* dst4 = (float4*)sm_stage;
    #pragma unroll
    for (int i = 0; i < 8; ++i)
        dst4[tid + i * THREADS] = src[tid + i * THREADS];
    if (tid < 64) dst4[tid + 2048] = src[tid + 2048];
    __syncthreads();

    // ---- 256 corner tasks: row = tid>>2, corner = tid&3; LDS addr tid*33 ----
    {
        const float* v = sm_stage + tid * 33;
        float x[33];
        #pragma unroll
        for (int k = 0; k < 33; ++k) x[k] = v[k];

        // top-4 descending (t0..t3), branchless insertion network
        float t0 = x[0], t1 = x[1], t2 = x[2], t3 = x[3];
        float a;
        a = fmaxf(t0, t1); t1 = fminf(t0, t1); t0 = a;
        a = fmaxf(t2, t3); t3 = fminf(t2, t3); t2 = a;
        a = fmaxf(t0, t2); t2 = fminf(t0, t2); t0 = a;
        a = fmaxf(t1, t3); t3 = fminf(t1, t3); t1 = a;
        a = fmaxf(t1, t2); t2 = fminf(t1, t2); t1 = a;
        #pragma unroll
        for (int k = 4; k < 33; ++k) {
            float xx = x[k];
            a = fmaxf(t0, xx); xx = fminf(t0, xx); t0 = a;
            a = fmaxf(t1, xx); xx = fminf(t1, xx); t1 = a;
            a = fmaxf(t2, xx); xx = fminf(t2, xx); t2 = a;
            t3 = fmaxf(t3, xx);
        }

        float s = 0.f;
        #pragma unroll
        for (int k = 0; k < 33; ++k) s += __expf(x[k] - t0);
        const float inv = 1.0f / s;
        const float p0 = inv;
        const float p1 = __expf(t1 - t0) * inv;
        const float p2 = __expf(t2 - t0) * inv;
        const float p3 = __expf(t3 - t0) * inv;
        const float pm = 0.25f * (p0 + p1 + p2 + p3);

        float* sd = sm_stat + (tid >> 2) * 21 + (tid & 3) * 5;
        sd[0] = p0; sd[1] = p1; sd[2] = p2; sd[3] = p3; sd[4] = pm;
    }
    __syncthreads();

    // ---- MLP: wave 0, one thread per row; weight indices wave-uniform ----
    if (tid < ROWS) {
        float st[20];
        #pragma unroll
        for (int k = 0; k < 20; ++k) st[k] = sm_stat[tid * 21 + k];

        float acc = 0.f;
        #pragma unroll
        for (int jc = 0; jc < 4; ++jc) {
            float h[16];
            #pragma unroll
            for (int j = 0; j < 16; ++j) h[j] = b1[jc * 16 + j];
            #pragma unroll
            for (int k = 0; k < 20; ++k) {
                #pragma unroll
                for (int j = 0; j < 16; ++j)
                    h[j] = fmaf(st[k], w1[k * 64 + jc * 16 + j], h[j]);
            }
            #pragma unroll
            for (int j = 0; j < 16; ++j)
                acc = fmaf(fmaxf(h[j], 0.f), w2[jc * 16 + j], acc);
        }

        const long long grow = rowBase + tid;
        out[grow] = scores[grow] + acc + b2[0];
    }
}

extern "C" void kernel_launch(void* const* d_in, const int* in_sizes, int n_in,
                              void* d_out, int out_size, void* d_ws, size_t ws_size,
                              hipStream_t stream) {
    const float* scores = (const float*)d_in[0];
    const float* pc     = (const float*)d_in[1];
    const float* w1     = (const float*)d_in[2];
    const float* b1     = (const float*)d_in[3];
    const float* w2     = (const float*)d_in[4];
    const float* b2     = (const float*)d_in[5];
    float* out = (float*)d_out;

    const int rows = out_size;            // 262144
    const int blocks = rows / ROWS;       // 4096
    lqe_kernel<<<blocks, THREADS, 0, stream>>>(scores, pc, w1, b1, w2, b2, out);
}

// Round 3
// 44.294 us; speedup vs baseline: 1.1652x; 1.1425x over previous
//
#include <hip/hip_runtime.h>

// Deimv2LQE: out = scores + MLP(top4-softmax-stats(pred_corners))
// 262144 rows; per row 132 f32 (4 corners x 33 bins).
// R3: barrier-free wave-autonomous blocks. Block = 64 threads (1 wave),
//     64 rows/block in 4 substages of 16 rows, software-pipelined
//     (issue next substage's global loads before computing current).
//     LDS 13824 B/block -> 11 blocks/CU. MLP lane-per-row, wave-uniform
//     weight indices -> s_load constant-cache path. No __syncthreads.

#define THREADS 64
#define ROWS 64
#define SUB 16   // rows per substage

__global__ __launch_bounds__(THREADS)
void lqe_kernel(const float* __restrict__ scores,
                const float* __restrict__ pc,
                const float* __restrict__ w1,
                const float* __restrict__ b1,
                const float* __restrict__ w2,
                const float* __restrict__ b2,
                float* __restrict__ out)
{
    __shared__ float sm_stage[SUB * 132];   // 8448 B, one substage of 16 rows
    __shared__ float sm_stat[ROWS * 21];    // 5376 B, stride 21 (odd -> <=2-way)

    const int l = threadIdx.x;
    const long long rowBase = (long long)blockIdx.x * ROWS;

    const float myScore = scores[rowBase + l];          // prefetch early

    const float4* src = (const float4*)(pc + rowBase * 132); // 2112 float4/block
    float4* dst4 = (float4*)sm_stage;

    // 528 float4 per substage = 8/lane + tail 16
    auto stage_load = [&](float4 (&r)[8], float4& t, int s) {
        const float4* p = src + s * 528;
        #pragma unroll
        for (int i = 0; i < 8; ++i) r[i] = p[l + i * 64];
        if (l < 16) t = p[512 + l];
    };
    auto stage_write = [&](float4 (&r)[8], float4& t) {
        #pragma unroll
        for (int i = 0; i < 8; ++i) dst4[l + i * 64] = r[i];
        if (l < 16) dst4[512 + l] = t;
    };
    // lane handles corner: row_local = s*16 + (l>>2), corner c = l&3.
    // LDS offset = 33*l (odd stride -> conflict-free).
    auto compute_sub = [&](int s) {
        const float* v = sm_stage + l * 33;
        float x[33];
        #pragma unroll
        for (int k = 0; k < 33; ++k) x[k] = v[k];

        float t0 = x[0], t1 = x[1], t2 = x[2], t3 = x[3];
        float a;
        a = fmaxf(t0, t1); t1 = fminf(t0, t1); t0 = a;
        a = fmaxf(t2, t3); t3 = fminf(t2, t3); t2 = a;
        a = fmaxf(t0, t2); t2 = fminf(t0, t2); t0 = a;
        a = fmaxf(t1, t3); t3 = fminf(t1, t3); t1 = a;
        a = fmaxf(t1, t2); t2 = fminf(t1, t2); t1 = a;
        #pragma unroll
        for (int k = 4; k < 33; ++k) {
            float xx = x[k];
            a = fmaxf(t0, xx); xx = fminf(t0, xx); t0 = a;
            a = fmaxf(t1, xx); xx = fminf(t1, xx); t1 = a;
            a = fmaxf(t2, xx); xx = fminf(t2, xx); t2 = a;
            t3 = fmaxf(t3, xx);
        }

        float ssum = 0.f;
        #pragma unroll
        for (int k = 0; k < 33; ++k) ssum += __expf(x[k] - t0);
        const float inv = 1.0f / ssum;
        const float p0 = inv;
        const float p1 = __expf(t1 - t0) * inv;
        const float p2 = __expf(t2 - t0) * inv;
        const float p3 = __expf(t3 - t0) * inv;
        const float pm = 0.25f * (p0 + p1 + p2 + p3);

        float* sd = sm_stat + (s * SUB + (l >> 2)) * 21 + (l & 3) * 5;
        sd[0] = p0; sd[1] = p1; sd[2] = p2; sd[3] = p3; sd[4] = pm;
    };

    float4 ra[8], rb[8], ta, tb;
    // pipelined: loads for s+1 in flight while computing s (in-order DS
    // semantics within a wave make read-before-overwrite safe, no barrier)
    stage_load(ra, ta, 0);
    stage_write(ra, ta);
    stage_load(rb, tb, 1);
    compute_sub(0);
    stage_write(rb, tb);
    stage_load(ra, ta, 2);
    compute_sub(1);
    stage_write(ra, ta);
    stage_load(rb, tb, 3);
    compute_sub(2);
    stage_write(rb, tb);
    compute_sub(3);

    // ---- MLP: lane-per-row, weight indices wave-uniform -> s_load ----
    float st[20];
    #pragma unroll
    for (int k = 0; k < 20; ++k) st[k] = sm_stat[l * 21 + k];

    float acc = 0.f;
    #pragma unroll
    for (int jc = 0; jc < 4; ++jc) {
        float h[16];
        #pragma unroll
        for (int j = 0; j < 16; ++j) h[j] = b1[jc * 16 + j];
        #pragma unroll
        for (int k = 0; k < 20; ++k) {
            #pragma unroll
            for (int j = 0; j < 16; ++j)
                h[j] = fmaf(st[k], w1[k * 64 + jc * 16 + j], h[j]);
        }
        #pragma unroll
        for (int j = 0; j < 16; ++j)
            acc = fmaf(fmaxf(h[j], 0.f), w2[jc * 16 + j], acc);
    }

    out[rowBase + l] = myScore + acc + b2[0];
}

extern "C" void kernel_launch(void* const* d_in, const int* in_sizes, int n_in,
                              void* d_out, int out_size, void* d_ws, size_t ws_size,
                              hipStream_t stream) {
    const float* scores = (const float*)d_in[0];
    const float* pc     = (const float*)d_in[1];
    const float* w1     = (const float*)d_in[2];
    const float* b1     = (const float*)d_in[3];
    const float* w2     = (const float*)d_in[4];
    const float* b2     = (const float*)d_in[5];
    float* out = (float*)d_out;

    const int rows = out_size;          // 262144
    const int blocks = rows / ROWS;     // 4096
    lqe_kernel<<<blocks, THREADS, 0, stream>>>(scores, pc, w1, b1, w2, b2, out);
}